// Round 5
// baseline (338.989 us; speedup 1.0000x reference)
//
#include <hip/hip_runtime.h>
#include <math.h>

#define B_    4096
#define DIN   640
#define DD    128
#define PP    12
#define INV_T 0.25f

typedef __bf16 bft;
typedef __attribute__((ext_vector_type(8))) __bf16 bf16x8;
typedef __attribute__((ext_vector_type(4))) float fx4;

// ---------------------------------------------------------------------------
// prep: split weights into bf16 hi/lo (a = hi + lo, hi = RN_bf16(a)).
// Layouts stay [n][k] row-major == MFMA B-operand layout.
// ---------------------------------------------------------------------------
__global__ __launch_bounds__(256) void prep_kernel(
    const float* __restrict__ gw1, const float* __restrict__ pw1,
    const float* __restrict__ gw2, const float* __restrict__ pw2,
    bft* __restrict__ w1hg, bft* __restrict__ w1lg,
    bft* __restrict__ w1hp, bft* __restrict__ w1lp,
    bft* __restrict__ w2hg, bft* __restrict__ w2lg,
    bft* __restrict__ w2hp, bft* __restrict__ w2lp)
{
  int idx = blockIdx.x * 256 + threadIdx.x;   // 0 .. 196607
  const float* src; bft *dh, *dl; int off;
  if (idx < 81920)       { src = gw1; dh = w1hg; dl = w1lg; off = idx; }
  else if (idx < 163840) { src = pw1; dh = w1hp; dl = w1lp; off = idx - 81920; }
  else if (idx < 180224) { src = gw2; dh = w2hg; dl = w2lg; off = idx - 163840; }
  else                   { src = pw2; dh = w2hp; dl = w2lp; off = idx - 180224; }
  float x = src[off];
  bft h = (bft)x;
  dh[off] = h;
  dl[off] = (bft)(x - (float)h);
}

// ---------------------------------------------------------------------------
// MFMA embed (split-bf16): Y = normalize(relu(X@W1^T+b1)@W2^T+b2).
// Block tile 64x128 (R4 was 128x128: 416 blocks @64KiB LDS -> 1.6 blocks/CU,
// occupancy 14%, latency-bound). Now: 832 blocks, 32 KiB LDS, 4 blocks/CU.
// 4 waves 2x2: wave tile 32x64 = 2x4 of 16x16x32. Static reg buffers only.
// Grid: blocks 0..63 = g-stream, 64..831 = p-stream.
// ---------------------------------------------------------------------------
__global__ __launch_bounds__(256, 4) void embed_kernel(
    const float* __restrict__ ebg, const float* __restrict__ ebp,
    const bft* __restrict__ w1hg, const bft* __restrict__ w1lg, const float* __restrict__ b1g,
    const bft* __restrict__ w2hg, const bft* __restrict__ w2lg, const float* __restrict__ b2g,
    const bft* __restrict__ w1hp, const bft* __restrict__ w1lp, const float* __restrict__ b1p,
    const bft* __restrict__ w2hp, const bft* __restrict__ w2lp, const float* __restrict__ b2p,
    float* __restrict__ outg, float* __restrict__ outp)
{
  __shared__ bft hsm[2 * 64 * 128];           // 32768 B
  bft* hhi = hsm;
  bft* hlo = hsm + 64 * 128;
  float* halfsq = (float*)hsm;                // aliased after h dead

  const int t = threadIdx.x;
  const int w = t >> 6, lane = t & 63;
  const int wm = w >> 1, wn = w & 1;
  const int ln = lane & 15, quad = lane >> 4;

  const float *X, *B1, *B2;
  const bft *W1H, *W1L, *W2H, *W2L;
  float* Y;
  long m0;
  if (blockIdx.x < 64) {
    X = ebg; W1H = w1hg; W1L = w1lg; B1 = b1g; W2H = w2hg; W2L = w2lg; B2 = b2g;
    Y = outg; m0 = (long)blockIdx.x * 64;
  } else {
    X = ebp; W1H = w1hp; W1L = w1lp; B1 = b1p; W2H = w2hp; W2L = w2lp; B2 = b2p;
    Y = outp; m0 = (long)(blockIdx.x - 64) * 64;
  }

  const float* xptr[2];
  const bft *p1h[4], *p1l[4];
#pragma unroll
  for (int mt = 0; mt < 2; mt++)
    xptr[mt] = X + (size_t)(m0 + wm * 32 + mt * 16 + ln) * DIN + quad * 8;
#pragma unroll
  for (int nt = 0; nt < 4; nt++) {
    int n = wn * 64 + nt * 16 + ln;
    p1h[nt] = W1H + (size_t)n * DIN + quad * 8;
    p1l[nt] = W1L + (size_t)n * DIN + quad * 8;
  }

  fx4 acc[2][4];
#pragma unroll
  for (int mt = 0; mt < 2; mt++)
#pragma unroll
    for (int nt = 0; nt < 4; nt++) acc[mt][nt] = (fx4){0.f, 0.f, 0.f, 0.f};

#define LOADX(dst, koff)                                   \
  _Pragma("unroll")                                        \
  for (int mt = 0; mt < 2; mt++) {                         \
    dst[mt][0] = *(const fx4*)(xptr[mt] + (koff));         \
    dst[mt][1] = *(const fx4*)(xptr[mt] + (koff) + 4);     \
  }

#define CONVX(src, ah, al)                                 \
  _Pragma("unroll")                                        \
  for (int mt = 0; mt < 2; mt++)                           \
    _Pragma("unroll")                                      \
    for (int q = 0; q < 2; q++)                            \
      _Pragma("unroll")                                    \
      for (int j = 0; j < 4; j++) {                        \
        float xv = src[mt][q][j];                          \
        bft hh = (bft)xv;                                  \
        ah[mt][q * 4 + j] = hh;                            \
        al[mt][q * 4 + j] = (bft)(xv - (float)hh);         \
      }

#define MFMA3(ah, al, k0)                                                              \
  {                                                                                    \
    bf16x8 bh[4], bl[4];                                                               \
    _Pragma("unroll")                                                                  \
    for (int nt = 0; nt < 4; nt++) {                                                   \
      bh[nt] = *(const bf16x8*)(p1h[nt] + (k0));                                       \
      bl[nt] = *(const bf16x8*)(p1l[nt] + (k0));                                       \
    }                                                                                  \
    _Pragma("unroll")                                                                  \
    for (int mt = 0; mt < 2; mt++)                                                     \
      _Pragma("unroll")                                                                \
      for (int nt = 0; nt < 4; nt++) {                                                 \
        acc[mt][nt] = __builtin_amdgcn_mfma_f32_16x16x32_bf16(ah[mt], bh[nt], acc[mt][nt], 0, 0, 0); \
        acc[mt][nt] = __builtin_amdgcn_mfma_f32_16x16x32_bf16(al[mt], bh[nt], acc[mt][nt], 0, 0, 0); \
        acc[mt][nt] = __builtin_amdgcn_mfma_f32_16x16x32_bf16(ah[mt], bl[nt], acc[mt][nt], 0, 0, 0); \
      }                                                                                \
  }

  // ---- phase 1: acc = X @ W1^T, k-loop unrolled x2, static double buffer ----
  fx4 xa[2][2], xb[2][2];
  bf16x8 ah[2], al[2];
  LOADX(xa, 0)
  for (int kc = 0; kc < 20; kc += 2) {
    const int k0 = kc * 32;
    LOADX(xb, k0 + 32)
    CONVX(xa, ah, al)
    MFMA3(ah, al, k0)
    if (kc < 18) { LOADX(xa, k0 + 64) }
    CONVX(xb, ah, al)
    MFMA3(ah, al, k0 + 32)
  }

  // ---- bias1 + relu, split h into LDS (XOR-swizzled 16B chunks) ----
  // element (m, c): addr = m*128 + ((c>>3) ^ (m&15))*8 + (c&7)
#pragma unroll
  for (int nt = 0; nt < 4; nt++) {
    float bv = B1[wn * 64 + nt * 16 + ln];
    int c8 = wn * 8 + nt * 2 + (ln >> 3);
    int c7 = ln & 7;
#pragma unroll
    for (int mt = 0; mt < 2; mt++) {
#pragma unroll
      for (int r = 0; r < 4; r++) {
        float v = fmaxf(acc[mt][nt][r] + bv, 0.f);
        bft h = (bft)v;
        bft l = (bft)(v - (float)h);
        int m = wm * 32 + mt * 16 + quad * 4 + r;
        int addr = m * 128 + ((c8 ^ (m & 15)) << 3) + c7;
        hhi[addr] = h;
        hlo[addr] = l;
      }
    }
  }
  __syncthreads();

  // ---- phase 2: acc2 = h @ W2^T + b2 (split-bf16) ----
  fx4 acc2[2][4];
#pragma unroll
  for (int nt = 0; nt < 4; nt++) {
    float bv = B2[wn * 64 + nt * 16 + ln];
#pragma unroll
    for (int mt = 0; mt < 2; mt++) acc2[mt][nt] = (fx4){bv, bv, bv, bv};
  }
  const bft *p2h[4], *p2l[4];
#pragma unroll
  for (int nt = 0; nt < 4; nt++) {
    int n = wn * 64 + nt * 16 + ln;
    p2h[nt] = W2H + (size_t)n * DD + quad * 8;
    p2l[nt] = W2L + (size_t)n * DD + quad * 8;
  }
#pragma unroll
  for (int kc = 0; kc < 4; kc++) {
    const int k0 = kc * 32;
    bf16x8 bh2[4], bl2[4], ah2[2], al2[2];
#pragma unroll
    for (int nt = 0; nt < 4; nt++) {
      bh2[nt] = *(const bf16x8*)(p2h[nt] + k0);
      bl2[nt] = *(const bf16x8*)(p2l[nt] + k0);
    }
#pragma unroll
    for (int mt = 0; mt < 2; mt++) {
      int m = wm * 32 + mt * 16 + ln;
      int c8 = (kc * 4 + quad) ^ ln;               // m&15 == ln
      ah2[mt] = *(const bf16x8*)&hhi[m * 128 + (c8 << 3)];
      al2[mt] = *(const bf16x8*)&hlo[m * 128 + (c8 << 3)];
    }
#pragma unroll
    for (int mt = 0; mt < 2; mt++)
#pragma unroll
      for (int nt = 0; nt < 4; nt++) {
        acc2[mt][nt] = __builtin_amdgcn_mfma_f32_16x16x32_bf16(ah2[mt], bh2[nt], acc2[mt][nt], 0, 0, 0);
        acc2[mt][nt] = __builtin_amdgcn_mfma_f32_16x16x32_bf16(al2[mt], bh2[nt], acc2[mt][nt], 0, 0, 0);
        acc2[mt][nt] = __builtin_amdgcn_mfma_f32_16x16x32_bf16(ah2[mt], bl2[nt], acc2[mt][nt], 0, 0, 0);
      }
  }
  __syncthreads();   // h reads done; halfsq may overwrite hsm

  // ---- row L2 normalize ----
#pragma unroll
  for (int mt = 0; mt < 2; mt++) {
#pragma unroll
    for (int r = 0; r < 4; r++) {
      float s = 0.f;
#pragma unroll
      for (int nt = 0; nt < 4; nt++) { float v = acc2[mt][nt][r]; s += v * v; }
      s += __shfl_xor(s, 1, 64);
      s += __shfl_xor(s, 2, 64);
      s += __shfl_xor(s, 4, 64);
      s += __shfl_xor(s, 8, 64);
      if (ln == 0) halfsq[(wm * 32 + mt * 16 + quad * 4 + r) * 2 + wn] = s;
    }
  }
  __syncthreads();
#pragma unroll
  for (int mt = 0; mt < 2; mt++) {
#pragma unroll
    for (int r = 0; r < 4; r++) {
      int row = wm * 32 + mt * 16 + quad * 4 + r;
      float rinv = 1.0f / sqrtf(halfsq[row * 2] + halfsq[row * 2 + 1]);
#pragma unroll
      for (int nt = 0; nt < 4; nt++)
        Y[(m0 + row) * DD + wn * 64 + nt * 16 + ln] = acc2[mt][nt][r] * rinv;
    }
  }
}

// ---------------------------------------------------------------------------
// Symmetric KL of one D=128 row pair per 64-lane wave; inputs pre-scaled 1/T.
// sym = sum_i (pu_i - pv_i)*(au_i - av_i)  (LSE terms cancel exactly).
// No max-subtraction: args bounded (|a|<=0.25 dil, [0,1] dcl) -> exp safe.
// ---------------------------------------------------------------------------
__device__ __forceinline__ float sym_kl_row(float au0, float au1, float av0, float av1)
{
  float eu0 = __expf(au0), eu1 = __expf(au1);
  float ev0 = __expf(av0), ev1 = __expf(av1);
  float su = eu0 + eu1, sv = ev0 + ev1;
#pragma unroll
  for (int o = 32; o > 0; o >>= 1) {
    su += __shfl_xor(su, o, 64);
    sv += __shfl_xor(sv, o, 64);
  }
  float ru = 1.0f / su, rv = 1.0f / sv;
  float d0 = au0 - av0, d1 = au1 - av1;
  float part = (eu0 * ru - ev0 * rv) * d0 + (eu1 * ru - ev1 * rv) * d1;
#pragma unroll
  for (int o = 32; o > 0; o >>= 1) part += __shfl_xor(part, o, 64);
  return part;
}

// ---------------------------------------------------------------------------
// Fused loss: one wave per b. Holds p[0..11][b] in regs (float2/lane), computes
// pbar, dil, and all 12 dcl terms in ONE pass over p.
// ---------------------------------------------------------------------------
__global__ __launch_bounds__(256) void loss_kernel(
    const float* __restrict__ g, const float* __restrict__ p,
    float* __restrict__ pdil, float* __restrict__ pdcl)
{
  __shared__ float wd[4], wc[4];
  int w = threadIdx.x >> 6, lane = threadIdx.x & 63;
  int b = blockIdx.x * 4 + w;
  float2 pl[PP];
  float sx = 0.f, sy = 0.f;
#pragma unroll
  for (int l = 0; l < PP; l++) {
    pl[l] = *(const float2*)&p[((size_t)l * B_ + b) * DD + lane * 2];
    sx += pl[l].x; sy += pl[l].y;
  }
  sx *= (1.0f / PP); sy *= (1.0f / PP);
  float2 gv = *(const float2*)&g[(size_t)b * DD + lane * 2];

  float dil = sym_kl_row(gv.x * INV_T, gv.y * INV_T, sx * INV_T, sy * INV_T) * 0.125f;

  float dcl = 0.f;
#pragma unroll
  for (int l = 0; l < PP; l++) {
    float u0 = (gv.x - pl[l].x) * (gv.x - pl[l].x) * INV_T;
    float u1 = (gv.y - pl[l].y) * (gv.y - pl[l].y) * INV_T;
    float v0 = (sx - pl[l].x) * (sx - pl[l].x) * INV_T;
    float v1 = (sy - pl[l].y) * (sy - pl[l].y) * INV_T;
    dcl += sym_kl_row(u0, u1, v0, v1);
  }
  dcl *= (1.0f / 96.0f);

  if (lane == 0) { wd[w] = dil; wc[w] = dcl; }
  __syncthreads();
  if (threadIdx.x == 0) pdil[blockIdx.x] = wd[0] + wd[1] + wd[2] + wd[3];
  if (threadIdx.x == 1) pdcl[blockIdx.x] = wc[0] + wc[1] + wc[2] + wc[3];
}

__global__ __launch_bounds__(256) void final_kernel(const float* __restrict__ pdil,
                                                    const float* __restrict__ pdcl,
                                                    float* __restrict__ out)
{
  __shared__ float red[8];
  int t = threadIdx.x;
  float s0 = 0.f, s1 = 0.f;
  for (int i = t; i < 1024; i += 256) { s0 += pdil[i]; s1 += pdcl[i]; }
#pragma unroll
  for (int o = 32; o > 0; o >>= 1) {
    s0 += __shfl_xor(s0, o, 64);
    s1 += __shfl_xor(s1, o, 64);
  }
  int wid = t >> 6, lane = t & 63;
  if (lane == 0) { red[wid] = s0; red[4 + wid] = s1; }
  __syncthreads();
  if (t == 0) out[0] = red[0] + red[1] + red[2] + red[3];
  if (t == 1) out[1] = red[4] + red[5] + red[6] + red[7];
}

extern "C" void kernel_launch(void* const* d_in, const int* in_sizes, int n_in,
                              void* d_out, int out_size, void* d_ws, size_t ws_size,
                              hipStream_t stream)
{
  const float* ebg = (const float*)d_in[0];
  const float* ebp = (const float*)d_in[1];
  const float* gw1 = (const float*)d_in[3];
  const float* gb1 = (const float*)d_in[4];
  const float* gw2 = (const float*)d_in[5];
  const float* gb2 = (const float*)d_in[6];
  const float* pw1 = (const float*)d_in[7];
  const float* pb1 = (const float*)d_in[8];
  const float* pw2 = (const float*)d_in[9];
  const float* pb2 = (const float*)d_in[10];
  float* out = (float*)d_out;

  float* ws   = (float*)d_ws;
  float* g    = ws;                           // 524288 f
  float* p    = g + (size_t)B_ * DD;          // 6291456 f
  float* pdil = p + (size_t)PP * B_ * DD;     // 1024 f
  float* pdcl = pdil + 1024;                  // 1024 f
  bft* wb     = (bft*)(pdcl + 1024);
  bft* w1hg = wb;                 bft* w1lg = w1hg + 81920;
  bft* w1hp = w1lg + 81920;       bft* w1lp = w1hp + 81920;
  bft* w2hg = w1lp + 81920;       bft* w2lg = w2hg + 16384;
  bft* w2hp = w2lg + 16384;       bft* w2lp = w2hp + 16384;

  prep_kernel<<<768, 256, 0, stream>>>(gw1, pw1, gw2, pw2,
                                       w1hg, w1lg, w1hp, w1lp,
                                       w2hg, w2lg, w2hp, w2lp);
  embed_kernel<<<832, 256, 0, stream>>>(ebg, ebp,
                                        w1hg, w1lg, gb1, w2hg, w2lg, gb2,
                                        w1hp, w1lp, pb1, w2hp, w2lp, pb2,
                                        g, p);
  loss_kernel<<<B_ / 4, 256, 0, stream>>>(g, p, pdil, pdcl);
  final_kernel<<<1, 256, 0, stream>>>(pdil, pdcl, out);
}

// Round 6
// 294.180 us; speedup vs baseline: 1.1523x; 1.1523x over previous
//
#include <hip/hip_runtime.h>
#include <math.h>

#define B_    4096
#define DIN   640
#define DD    128
#define PP    12
#define INV_T 0.25f

typedef __bf16 bft;
typedef __attribute__((ext_vector_type(8))) __bf16 bf16x8;
typedef __attribute__((ext_vector_type(4))) float fx4;

// ---------------------------------------------------------------------------
// prep: split weights into bf16 hi/lo (a = hi + lo, hi = RN_bf16(a)).
// Layouts stay [n][k] row-major == MFMA B-operand layout.
// ---------------------------------------------------------------------------
__global__ __launch_bounds__(256) void prep_kernel(
    const float* __restrict__ gw1, const float* __restrict__ pw1,
    const float* __restrict__ gw2, const float* __restrict__ pw2,
    bft* __restrict__ w1hg, bft* __restrict__ w1lg,
    bft* __restrict__ w1hp, bft* __restrict__ w1lp,
    bft* __restrict__ w2hg, bft* __restrict__ w2lg,
    bft* __restrict__ w2hp, bft* __restrict__ w2lp)
{
  int idx = blockIdx.x * 256 + threadIdx.x;   // 0 .. 196607
  const float* src; bft *dh, *dl; int off;
  if (idx < 81920)       { src = gw1; dh = w1hg; dl = w1lg; off = idx; }
  else if (idx < 163840) { src = pw1; dh = w1hp; dl = w1lp; off = idx - 81920; }
  else if (idx < 180224) { src = gw2; dh = w2hg; dl = w2lg; off = idx - 163840; }
  else                   { src = pw2; dh = w2hp; dl = w2lp; off = idx - 180224; }
  float x = src[off];
  bft h = (bft)x;
  dh[off] = h;
  dl[off] = (bft)(x - (float)h);
}

// ---------------------------------------------------------------------------
// MFMA embed (split-bf16): Y = normalize(relu(X@W1^T+b1)@W2^T+b2).
// R6: back to 128x128 block tile (R4's best compute:load ratio; R5's 64x128
// halved it and regressed). NEW: W1 hi/lo fragments register-pipelined one
// k-chunk ahead (R4 loaded them inside the MFMA block -> naked vmcnt stall
// each chunk at 1.6 waves/SIMD). Phase-2 W2 frags hoisted across the barrier.
// Grid is the occupancy limit (416 blocks = 1.6 blocks/CU) so VGPR<=256 is
// free: __launch_bounds__(256,2).
// Grid: blocks 0..31 = g-stream, 32..415 = p-stream.
// ---------------------------------------------------------------------------
__global__ __launch_bounds__(256, 2) void embed_kernel(
    const float* __restrict__ ebg, const float* __restrict__ ebp,
    const bft* __restrict__ w1hg, const bft* __restrict__ w1lg, const float* __restrict__ b1g,
    const bft* __restrict__ w2hg, const bft* __restrict__ w2lg, const float* __restrict__ b2g,
    const bft* __restrict__ w1hp, const bft* __restrict__ w1lp, const float* __restrict__ b1p,
    const bft* __restrict__ w2hp, const bft* __restrict__ w2lp, const float* __restrict__ b2p,
    float* __restrict__ outg, float* __restrict__ outp)
{
  __shared__ bft hsm[2 * 128 * 128];          // 65536 B
  bft* hhi = hsm;
  bft* hlo = hsm + 128 * 128;
  float* halfsq = (float*)hsm;                // aliased after h dead

  const int t = threadIdx.x;
  const int w = t >> 6, lane = t & 63;
  const int wm = w >> 1, wn = w & 1;
  const int ln = lane & 15, quad = lane >> 4;

  const float *X, *B1, *B2;
  const bft *W1H, *W1L, *W2H, *W2L;
  float* Y;
  long m0;
  if (blockIdx.x < 32) {
    X = ebg; W1H = w1hg; W1L = w1lg; B1 = b1g; W2H = w2hg; W2L = w2lg; B2 = b2g;
    Y = outg; m0 = (long)blockIdx.x * 128;
  } else {
    X = ebp; W1H = w1hp; W1L = w1lp; B1 = b1p; W2H = w2hp; W2L = w2lp; B2 = b2p;
    Y = outp; m0 = (long)(blockIdx.x - 32) * 128;
  }

  const float* xptr[4];
  const bft *p1h[4], *p1l[4];
#pragma unroll
  for (int mt = 0; mt < 4; mt++)
    xptr[mt] = X + (size_t)(m0 + wm * 64 + mt * 16 + ln) * DIN + quad * 8;
#pragma unroll
  for (int nt = 0; nt < 4; nt++) {
    int n = wn * 64 + nt * 16 + ln;
    p1h[nt] = W1H + (size_t)n * DIN + quad * 8;
    p1l[nt] = W1L + (size_t)n * DIN + quad * 8;
  }

  fx4 acc[4][4];
#pragma unroll
  for (int mt = 0; mt < 4; mt++)
#pragma unroll
    for (int nt = 0; nt < 4; nt++) acc[mt][nt] = (fx4){0.f, 0.f, 0.f, 0.f};

#define LOADX(dst, koff)                                   \
  _Pragma("unroll")                                        \
  for (int mt = 0; mt < 4; mt++) {                         \
    dst[mt][0] = *(const fx4*)(xptr[mt] + (koff));         \
    dst[mt][1] = *(const fx4*)(xptr[mt] + (koff) + 4);     \
  }

#define LOADW(wh, wl, koff)                                \
  _Pragma("unroll")                                        \
  for (int nt = 0; nt < 4; nt++) {                         \
    wh[nt] = *(const bf16x8*)(p1h[nt] + (koff));           \
    wl[nt] = *(const bf16x8*)(p1l[nt] + (koff));           \
  }

#define CONVX(src, ah, al)                                 \
  _Pragma("unroll")                                        \
  for (int mt = 0; mt < 4; mt++)                           \
    _Pragma("unroll")                                      \
    for (int q = 0; q < 2; q++)                            \
      _Pragma("unroll")                                    \
      for (int j = 0; j < 4; j++) {                        \
        float xv = src[mt][q][j];                          \
        bft hh = (bft)xv;                                  \
        ah[mt][q * 4 + j] = hh;                            \
        al[mt][q * 4 + j] = (bft)(xv - (float)hh);         \
      }

#define MFMA3R(ah, al, wh, wl)                                                         \
  _Pragma("unroll")                                                                    \
  for (int mt = 0; mt < 4; mt++)                                                       \
    _Pragma("unroll")                                                                  \
    for (int nt = 0; nt < 4; nt++) {                                                   \
      acc[mt][nt] = __builtin_amdgcn_mfma_f32_16x16x32_bf16(ah[mt], wh[nt], acc[mt][nt], 0, 0, 0); \
      acc[mt][nt] = __builtin_amdgcn_mfma_f32_16x16x32_bf16(al[mt], wh[nt], acc[mt][nt], 0, 0, 0); \
      acc[mt][nt] = __builtin_amdgcn_mfma_f32_16x16x32_bf16(ah[mt], wl[nt], acc[mt][nt], 0, 0, 0); \
    }

  // ---- phase 1: acc = X @ W1^T; X and W both pipelined one chunk ahead ----
  fx4 xa[4][2], xb[4][2];
  bf16x8 ah[4], al[4];
  bf16x8 wha[4], wla[4], whb[4], wlb[4];
  LOADX(xa, 0)
  LOADW(wha, wla, 0)
  for (int kc = 0; kc < 20; kc += 2) {
    const int k0 = kc * 32;
    LOADX(xb, k0 + 32)
    LOADW(whb, wlb, k0 + 32)
    CONVX(xa, ah, al)
    MFMA3R(ah, al, wha, wla)
    if (kc < 18) {
      LOADX(xa, k0 + 64)
      LOADW(wha, wla, k0 + 64)
    }
    CONVX(xb, ah, al)
    MFMA3R(ah, al, whb, wlb)
  }

  // ---- bias1 + relu, split h into LDS (XOR-swizzled 16B chunks) ----
  // element (m, c): addr = m*128 + ((c>>3) ^ (m&15))*8 + (c&7)
#pragma unroll
  for (int nt = 0; nt < 4; nt++) {
    float bv = B1[wn * 64 + nt * 16 + ln];
    int c8 = wn * 8 + nt * 2 + (ln >> 3);
    int c7 = ln & 7;
#pragma unroll
    for (int mt = 0; mt < 4; mt++) {
#pragma unroll
      for (int r = 0; r < 4; r++) {
        float v = fmaxf(acc[mt][nt][r] + bv, 0.f);
        bft h = (bft)v;
        bft l = (bft)(v - (float)h);
        int m = wm * 64 + mt * 16 + quad * 4 + r;
        int addr = m * 128 + ((c8 ^ (m & 15)) << 3) + c7;
        hhi[addr] = h;
        hlo[addr] = l;
      }
    }
  }

  // ---- phase 2: acc2 = h @ W2^T + b2 (split-bf16), W2 pipelined ----
  const bft *p2h[4], *p2l[4];
#pragma unroll
  for (int nt = 0; nt < 4; nt++) {
    int n = wn * 64 + nt * 16 + ln;
    p2h[nt] = W2H + (size_t)n * DD + quad * 8;
    p2l[nt] = W2L + (size_t)n * DD + quad * 8;
  }
  fx4 acc2[4][4];
#pragma unroll
  for (int nt = 0; nt < 4; nt++) {
    float bv = B2[wn * 64 + nt * 16 + ln];
#pragma unroll
    for (int mt = 0; mt < 4; mt++) acc2[mt][nt] = (fx4){bv, bv, bv, bv};
  }

#define LOADW2(wh, wl, koff)                               \
  _Pragma("unroll")                                        \
  for (int nt = 0; nt < 4; nt++) {                         \
    wh[nt] = *(const bf16x8*)(p2h[nt] + (koff));           \
    wl[nt] = *(const bf16x8*)(p2l[nt] + (koff));           \
  }

#define PH2CHUNK(kcv, wh, wl)                                                          \
  {                                                                                    \
    bf16x8 ah2[4], al2[4];                                                             \
    _Pragma("unroll")                                                                  \
    for (int mt = 0; mt < 4; mt++) {                                                   \
      int m = wm * 64 + mt * 16 + ln;                                                  \
      int c8 = ((kcv) * 4 + quad) ^ (m & 15);                                          \
      ah2[mt] = *(const bf16x8*)&hhi[m * 128 + (c8 << 3)];                             \
      al2[mt] = *(const bf16x8*)&hlo[m * 128 + (c8 << 3)];                             \
    }                                                                                  \
    _Pragma("unroll")                                                                  \
    for (int mt = 0; mt < 4; mt++)                                                     \
      _Pragma("unroll")                                                                \
      for (int nt = 0; nt < 4; nt++) {                                                 \
        acc2[mt][nt] = __builtin_amdgcn_mfma_f32_16x16x32_bf16(ah2[mt], wh[nt], acc2[mt][nt], 0, 0, 0); \
        acc2[mt][nt] = __builtin_amdgcn_mfma_f32_16x16x32_bf16(al2[mt], wh[nt], acc2[mt][nt], 0, 0, 0); \
        acc2[mt][nt] = __builtin_amdgcn_mfma_f32_16x16x32_bf16(ah2[mt], wl[nt], acc2[mt][nt], 0, 0, 0); \
      }                                                                                \
  }

  bf16x8 q2ha[4], q2la[4], q2hb[4], q2lb[4];
  LOADW2(q2ha, q2la, 0)        // issued pre-barrier: barrier hides the latency
  __syncthreads();
  LOADW2(q2hb, q2lb, 32)
  PH2CHUNK(0, q2ha, q2la)
  LOADW2(q2ha, q2la, 64)
  PH2CHUNK(1, q2hb, q2lb)
  LOADW2(q2hb, q2lb, 96)
  PH2CHUNK(2, q2ha, q2la)
  PH2CHUNK(3, q2hb, q2lb)
  __syncthreads();   // h reads done; halfsq may overwrite hsm

  // ---- row L2 normalize ----
#pragma unroll
  for (int mt = 0; mt < 4; mt++) {
#pragma unroll
    for (int r = 0; r < 4; r++) {
      float s = 0.f;
#pragma unroll
      for (int nt = 0; nt < 4; nt++) { float v = acc2[mt][nt][r]; s += v * v; }
      s += __shfl_xor(s, 1, 64);
      s += __shfl_xor(s, 2, 64);
      s += __shfl_xor(s, 4, 64);
      s += __shfl_xor(s, 8, 64);
      if (ln == 0) halfsq[(wm * 64 + mt * 16 + quad * 4 + r) * 2 + wn] = s;
    }
  }
  __syncthreads();
#pragma unroll
  for (int mt = 0; mt < 4; mt++) {
#pragma unroll
    for (int r = 0; r < 4; r++) {
      int row = wm * 64 + mt * 16 + quad * 4 + r;
      float rinv = 1.0f / sqrtf(halfsq[row * 2] + halfsq[row * 2 + 1]);
#pragma unroll
      for (int nt = 0; nt < 4; nt++)
        Y[(m0 + row) * DD + wn * 64 + nt * 16 + ln] = acc2[mt][nt][r] * rinv;
    }
  }
}

// ---------------------------------------------------------------------------
// Symmetric KL of one D=128 row pair per 64-lane wave; inputs pre-scaled 1/T.
// sym = sum_i (pu_i - pv_i)*(au_i - av_i)  (LSE terms cancel exactly).
// No max-subtraction: args bounded (|a|<=0.25 dil, [0,1] dcl) -> exp safe.
// ---------------------------------------------------------------------------
__device__ __forceinline__ float sym_kl_row(float au0, float au1, float av0, float av1)
{
  float eu0 = __expf(au0), eu1 = __expf(au1);
  float ev0 = __expf(av0), ev1 = __expf(av1);
  float su = eu0 + eu1, sv = ev0 + ev1;
#pragma unroll
  for (int o = 32; o > 0; o >>= 1) {
    su += __shfl_xor(su, o, 64);
    sv += __shfl_xor(sv, o, 64);
  }
  float ru = 1.0f / su, rv = 1.0f / sv;
  float d0 = au0 - av0, d1 = au1 - av1;
  float part = (eu0 * ru - ev0 * rv) * d0 + (eu1 * ru - ev1 * rv) * d1;
#pragma unroll
  for (int o = 32; o > 0; o >>= 1) part += __shfl_xor(part, o, 64);
  return part;
}

// ---------------------------------------------------------------------------
// Fused loss: one wave per b. Holds p[0..11][b] in regs (float2/lane), computes
// pbar, dil, and all 12 dcl terms in ONE pass over p.
// ---------------------------------------------------------------------------
__global__ __launch_bounds__(256) void loss_kernel(
    const float* __restrict__ g, const float* __restrict__ p,
    float* __restrict__ pdil, float* __restrict__ pdcl)
{
  __shared__ float wd[4], wc[4];
  int w = threadIdx.x >> 6, lane = threadIdx.x & 63;
  int b = blockIdx.x * 4 + w;
  float2 pl[PP];
  float sx = 0.f, sy = 0.f;
#pragma unroll
  for (int l = 0; l < PP; l++) {
    pl[l] = *(const float2*)&p[((size_t)l * B_ + b) * DD + lane * 2];
    sx += pl[l].x; sy += pl[l].y;
  }
  sx *= (1.0f / PP); sy *= (1.0f / PP);
  float2 gv = *(const float2*)&g[(size_t)b * DD + lane * 2];

  float dil = sym_kl_row(gv.x * INV_T, gv.y * INV_T, sx * INV_T, sy * INV_T) * 0.125f;

  float dcl = 0.f;
#pragma unroll
  for (int l = 0; l < PP; l++) {
    float u0 = (gv.x - pl[l].x) * (gv.x - pl[l].x) * INV_T;
    float u1 = (gv.y - pl[l].y) * (gv.y - pl[l].y) * INV_T;
    float v0 = (sx - pl[l].x) * (sx - pl[l].x) * INV_T;
    float v1 = (sy - pl[l].y) * (sy - pl[l].y) * INV_T;
    dcl += sym_kl_row(u0, u1, v0, v1);
  }
  dcl *= (1.0f / 96.0f);

  if (lane == 0) { wd[w] = dil; wc[w] = dcl; }
  __syncthreads();
  if (threadIdx.x == 0) pdil[blockIdx.x] = wd[0] + wd[1] + wd[2] + wd[3];
  if (threadIdx.x == 1) pdcl[blockIdx.x] = wc[0] + wc[1] + wc[2] + wc[3];
}

__global__ __launch_bounds__(256) void final_kernel(const float* __restrict__ pdil,
                                                    const float* __restrict__ pdcl,
                                                    float* __restrict__ out)
{
  __shared__ float red[8];
  int t = threadIdx.x;
  float s0 = 0.f, s1 = 0.f;
  for (int i = t; i < 1024; i += 256) { s0 += pdil[i]; s1 += pdcl[i]; }
#pragma unroll
  for (int o = 32; o > 0; o >>= 1) {
    s0 += __shfl_xor(s0, o, 64);
    s1 += __shfl_xor(s1, o, 64);
  }
  int wid = t >> 6, lane = t & 63;
  if (lane == 0) { red[wid] = s0; red[4 + wid] = s1; }
  __syncthreads();
  if (t == 0) out[0] = red[0] + red[1] + red[2] + red[3];
  if (t == 1) out[1] = red[4] + red[5] + red[6] + red[7];
}

extern "C" void kernel_launch(void* const* d_in, const int* in_sizes, int n_in,
                              void* d_out, int out_size, void* d_ws, size_t ws_size,
                              hipStream_t stream)
{
  const float* ebg = (const float*)d_in[0];
  const float* ebp = (const float*)d_in[1];
  const float* gw1 = (const float*)d_in[3];
  const float* gb1 = (const float*)d_in[4];
  const float* gw2 = (const float*)d_in[5];
  const float* gb2 = (const float*)d_in[6];
  const float* pw1 = (const float*)d_in[7];
  const float* pb1 = (const float*)d_in[8];
  const float* pw2 = (const float*)d_in[9];
  const float* pb2 = (const float*)d_in[10];
  float* out = (float*)d_out;

  float* ws   = (float*)d_ws;
  float* g    = ws;                           // 524288 f
  float* p    = g + (size_t)B_ * DD;          // 6291456 f
  float* pdil = p + (size_t)PP * B_ * DD;     // 1024 f
  float* pdcl = pdil + 1024;                  // 1024 f
  bft* wb     = (bft*)(pdcl + 1024);
  bft* w1hg = wb;                 bft* w1lg = w1hg + 81920;
  bft* w1hp = w1lg + 81920;       bft* w1lp = w1hp + 81920;
  bft* w2hg = w1lp + 81920;       bft* w2lg = w2hg + 16384;
  bft* w2hp = w2lg + 16384;       bft* w2lp = w2hp + 16384;

  prep_kernel<<<768, 256, 0, stream>>>(gw1, pw1, gw2, pw2,
                                       w1hg, w1lg, w1hp, w1lp,
                                       w2hg, w2lg, w2hp, w2lp);
  embed_kernel<<<416, 256, 0, stream>>>(ebg, ebp,
                                        w1hg, w1lg, gb1, w2hg, w2lg, gb2,
                                        w1hp, w1lp, pb1, w2hp, w2lp, pb2,
                                        g, p);
  loss_kernel<<<B_ / 4, 256, 0, stream>>>(g, p, pdil, pdcl);
  final_kernel<<<1, 256, 0, stream>>>(pdil, pdcl, out);
}

// Round 7
// 267.792 us; speedup vs baseline: 1.2659x; 1.0985x over previous
//
#include <hip/hip_runtime.h>
#include <math.h>

#define B_    4096
#define DIN   640
#define DD    128
#define PP    12
#define INV_T 0.25f

typedef __bf16 bft;
typedef __attribute__((ext_vector_type(8))) __bf16 bf16x8;
typedef __attribute__((ext_vector_type(4))) float fx4;

// async 16B global -> LDS (DMA, vmcnt-tracked, no VGPR round trip)
__device__ __forceinline__ void gload16(const float* gp, float* lp) {
  __builtin_amdgcn_global_load_lds(
      (const __attribute__((address_space(1))) unsigned int*)gp,
      (__attribute__((address_space(3))) unsigned int*)lp,
      16, 0, 0);
}

// ---------------------------------------------------------------------------
// prep: split weights into bf16 hi/lo (a = hi + lo, hi = RN_bf16(a)).
// ---------------------------------------------------------------------------
__global__ __launch_bounds__(256) void prep_kernel(
    const float* __restrict__ gw1, const float* __restrict__ pw1,
    const float* __restrict__ gw2, const float* __restrict__ pw2,
    bft* __restrict__ w1hg, bft* __restrict__ w1lg,
    bft* __restrict__ w1hp, bft* __restrict__ w1lp,
    bft* __restrict__ w2hg, bft* __restrict__ w2lg,
    bft* __restrict__ w2hp, bft* __restrict__ w2lp)
{
  int idx = blockIdx.x * 256 + threadIdx.x;   // 0 .. 196607
  const float* src; bft *dh, *dl; int off;
  if (idx < 81920)       { src = gw1; dh = w1hg; dl = w1lg; off = idx; }
  else if (idx < 163840) { src = pw1; dh = w1hp; dl = w1lp; off = idx - 81920; }
  else if (idx < 180224) { src = gw2; dh = w2hg; dl = w2lg; off = idx - 163840; }
  else                   { src = pw2; dh = w2hp; dl = w2lp; off = idx - 180224; }
  float x = src[off];
  bft h = (bft)x;
  dh[off] = h;
  dl[off] = (bft)(x - (float)h);
}

// ---------------------------------------------------------------------------
// MFMA embed (split-bf16): Y = normalize(relu(X@W1^T+b1)@W2^T+b2).
// R7: X staged via async global_load_lds (m97 pattern), double-buffered
// 128x32 fp32 tiles in LDS, one barrier per chunk: chunk k+1's DMA overlaps
// chunk k's MFMA (R6 was demand-latency-bound: 71 MB @ 800 GB/s = the whole
// kernel). X-tile slots XOR-swizzled (slot = kq ^ (row&7)) on the GLOBAL side
// so staging stays lane-contiguous and ds_read_b128 phases hit all 32 banks.
// xbuf (2x16 KB) aliases the h region; LDS = 64 KB, 2 blocks/CU.
// Grid: blocks 0..31 = g-stream, 32..415 = p-stream.
// ---------------------------------------------------------------------------
__global__ __launch_bounds__(256, 2) void embed_kernel(
    const float* __restrict__ ebg, const float* __restrict__ ebp,
    const bft* __restrict__ w1hg, const bft* __restrict__ w1lg, const float* __restrict__ b1g,
    const bft* __restrict__ w2hg, const bft* __restrict__ w2lg, const float* __restrict__ b2g,
    const bft* __restrict__ w1hp, const bft* __restrict__ w1lp, const float* __restrict__ b1p,
    const bft* __restrict__ w2hp, const bft* __restrict__ w2lp, const float* __restrict__ b2p,
    float* __restrict__ outg, float* __restrict__ outp)
{
  __shared__ bft hsm[2 * 128 * 128];          // 65536 B
  float* xb0 = (float*)hsm;                   // [128][32] fp32, 16 KB (aliases h)
  float* xb1 = xb0 + 4096;                    // second buffer, 16 KB
  bft* hhi = hsm;
  bft* hlo = hsm + 128 * 128;
  float* halfsq = (float*)hsm;                // aliased after h dead

  const int t = threadIdx.x;
  const int w = t >> 6, lane = t & 63;
  const int wm = w >> 1, wn = w & 1;
  const int ln = lane & 15, quad = lane >> 4;

  const float *X, *B1, *B2;
  const bft *W1H, *W1L, *W2H, *W2L;
  float* Y;
  long m0;
  if (blockIdx.x < 32) {
    X = ebg; W1H = w1hg; W1L = w1lg; B1 = b1g; W2H = w2hg; W2L = w2lg; B2 = b2g;
    Y = outg; m0 = (long)blockIdx.x * 128;
  } else {
    X = ebp; W1H = w1hp; W1L = w1lp; B1 = b1p; W2H = w2hp; W2L = w2lp; B2 = b2p;
    Y = outp; m0 = (long)(blockIdx.x - 32) * 128;
  }

  // staging coords: wave w fills rows w*32..w*32+31; 4 instrs of 64 lanes.
  // lane -> row_local = j*8 + (lane>>3), slot = lane&7, global kq = slot^(row&7)
  const int srow = lane >> 3;                       // 0..7
  const int skq  = (lane & 7) ^ srow;               // swizzled k-quad
  const float* xsrc = X + (size_t)(m0 + w * 32 + srow) * DIN + skq * 4;
  // LDS dest fp32 index for (wave w, instr j): (w*32 + j*8)*32 + lane*4
  const int ldst = w * 32 * 32 + lane * 4;

#define GLX(bufp, k0)                                        \
  _Pragma("unroll")                                          \
  for (int j = 0; j < 4; j++)                                \
    gload16(xsrc + (size_t)j * 8 * DIN + (k0), (bufp) + ldst + j * 8 * 32);

  // MFMA A-fragment read coords: m = wm*64+mt*16+ln, slots s0,s0^1
  const int s0 = ((quad << 1) ^ (ln & 7));

  const bft *p1h[4], *p1l[4];
#pragma unroll
  for (int nt = 0; nt < 4; nt++) {
    int n = wn * 64 + nt * 16 + ln;
    p1h[nt] = W1H + (size_t)n * DIN + quad * 8;
    p1l[nt] = W1L + (size_t)n * DIN + quad * 8;
  }

  fx4 acc[4][4];
#pragma unroll
  for (int mt = 0; mt < 4; mt++)
#pragma unroll
    for (int nt = 0; nt < 4; nt++) acc[mt][nt] = (fx4){0.f, 0.f, 0.f, 0.f};

#define LOADW(wh, wl, koff)                                \
  _Pragma("unroll")                                        \
  for (int nt = 0; nt < 4; nt++) {                         \
    wh[nt] = *(const bf16x8*)(p1h[nt] + (koff));           \
    wl[nt] = *(const bf16x8*)(p1l[nt] + (koff));           \
  }

#define PH1CHUNK(bufp, wh, wl)                                                         \
  {                                                                                    \
    bf16x8 ah[4], al[4];                                                               \
    _Pragma("unroll")                                                                  \
    for (int mt = 0; mt < 4; mt++) {                                                   \
      const float* rp = (bufp) + (wm * 64 + mt * 16 + ln) * 32;                        \
      fx4 x0 = *(const fx4*)(rp + s0 * 4);                                             \
      fx4 x1 = *(const fx4*)(rp + (s0 ^ 1) * 4);                                       \
      _Pragma("unroll")                                                                \
      for (int j = 0; j < 4; j++) {                                                    \
        float xv = x0[j];                                                              \
        bft hh = (bft)xv;                                                              \
        ah[mt][j] = hh;                                                                \
        al[mt][j] = (bft)(xv - (float)hh);                                             \
        float yv = x1[j];                                                              \
        bft hh2 = (bft)yv;                                                             \
        ah[mt][4 + j] = hh2;                                                           \
        al[mt][4 + j] = (bft)(yv - (float)hh2);                                        \
      }                                                                                \
    }                                                                                  \
    _Pragma("unroll")                                                                  \
    for (int mt = 0; mt < 4; mt++)                                                     \
      _Pragma("unroll")                                                                \
      for (int nt = 0; nt < 4; nt++) {                                                 \
        acc[mt][nt] = __builtin_amdgcn_mfma_f32_16x16x32_bf16(ah[mt], wh[nt], acc[mt][nt], 0, 0, 0); \
        acc[mt][nt] = __builtin_amdgcn_mfma_f32_16x16x32_bf16(al[mt], wh[nt], acc[mt][nt], 0, 0, 0); \
        acc[mt][nt] = __builtin_amdgcn_mfma_f32_16x16x32_bf16(ah[mt], wl[nt], acc[mt][nt], 0, 0, 0); \
      }                                                                                \
  }

  // ---- phase 1: async-staged K loop, unrolled x2 (static W reg buffers) ----
  bf16x8 wha[4], wla[4], whb[4], wlb[4];
  GLX(xb0, 0)
  LOADW(wha, wla, 0)
  __syncthreads();                       // drain chunk 0 DMA
  for (int kc = 0; kc < 20; kc += 2) {
    const int k0 = kc * 32;
    GLX(xb1, k0 + 32)                    // chunk kc+1 (always <= 19)
    LOADW(whb, wlb, k0 + 32)
    PH1CHUNK(xb0, wha, wla)
    __syncthreads();                     // drain kc+1 DMA; xb0 free
    if (kc < 18) {
      GLX(xb0, k0 + 64)
      LOADW(wha, wla, k0 + 64)
    }
    PH1CHUNK(xb1, whb, wlb)
    __syncthreads();                     // drain kc+2 DMA; xb1 free
  }

  // ---- bias1 + relu, split h into LDS (XOR-swizzled 16B chunks) ----
  // (loop's final barrier: all xbuf reads done; safe to overwrite via h)
#pragma unroll
  for (int nt = 0; nt < 4; nt++) {
    float bv = B1[wn * 64 + nt * 16 + ln];
    int c8 = wn * 8 + nt * 2 + (ln >> 3);
    int c7 = ln & 7;
#pragma unroll
    for (int mt = 0; mt < 4; mt++) {
#pragma unroll
      for (int r = 0; r < 4; r++) {
        float v = fmaxf(acc[mt][nt][r] + bv, 0.f);
        bft h = (bft)v;
        bft l = (bft)(v - (float)h);
        int m = wm * 64 + mt * 16 + quad * 4 + r;
        int addr = m * 128 + ((c8 ^ (m & 15)) << 3) + c7;
        hhi[addr] = h;
        hlo[addr] = l;
      }
    }
  }

  // ---- phase 2: acc2 = h @ W2^T + b2 (split-bf16), W2 pipelined ----
  const bft *p2h[4], *p2l[4];
#pragma unroll
  for (int nt = 0; nt < 4; nt++) {
    int n = wn * 64 + nt * 16 + ln;
    p2h[nt] = W2H + (size_t)n * DD + quad * 8;
    p2l[nt] = W2L + (size_t)n * DD + quad * 8;
  }
  fx4 acc2[4][4];
#pragma unroll
  for (int nt = 0; nt < 4; nt++) {
    float bv = B2[wn * 64 + nt * 16 + ln];
#pragma unroll
    for (int mt = 0; mt < 4; mt++) acc2[mt][nt] = (fx4){bv, bv, bv, bv};
  }

#define LOADW2(wh, wl, koff)                               \
  _Pragma("unroll")                                        \
  for (int nt = 0; nt < 4; nt++) {                         \
    wh[nt] = *(const bf16x8*)(p2h[nt] + (koff));           \
    wl[nt] = *(const bf16x8*)(p2l[nt] + (koff));           \
  }

#define PH2CHUNK(kcv, wh, wl)                                                          \
  {                                                                                    \
    bf16x8 ah2[4], al2[4];                                                             \
    _Pragma("unroll")                                                                  \
    for (int mt = 0; mt < 4; mt++) {                                                   \
      int m = wm * 64 + mt * 16 + ln;                                                  \
      int c8 = ((kcv) * 4 + quad) ^ (m & 15);                                          \
      ah2[mt] = *(const bf16x8*)&hhi[m * 128 + (c8 << 3)];                             \
      al2[mt] = *(const bf16x8*)&hlo[m * 128 + (c8 << 3)];                             \
    }                                                                                  \
    _Pragma("unroll")                                                                  \
    for (int mt = 0; mt < 4; mt++)                                                     \
      _Pragma("unroll")                                                                \
      for (int nt = 0; nt < 4; nt++) {                                                 \
        acc2[mt][nt] = __builtin_amdgcn_mfma_f32_16x16x32_bf16(ah2[mt], wh[nt], acc2[mt][nt], 0, 0, 0); \
        acc2[mt][nt] = __builtin_amdgcn_mfma_f32_16x16x32_bf16(al2[mt], wh[nt], acc2[mt][nt], 0, 0, 0); \
        acc2[mt][nt] = __builtin_amdgcn_mfma_f32_16x16x32_bf16(ah2[mt], wl[nt], acc2[mt][nt], 0, 0, 0); \
      }                                                                                \
  }

  bf16x8 q2ha[4], q2la[4], q2hb[4], q2lb[4];
  LOADW2(q2ha, q2la, 0)        // issued pre-barrier: barrier hides the latency
  __syncthreads();
  LOADW2(q2hb, q2lb, 32)
  PH2CHUNK(0, q2ha, q2la)
  LOADW2(q2ha, q2la, 64)
  PH2CHUNK(1, q2hb, q2lb)
  LOADW2(q2hb, q2lb, 96)
  PH2CHUNK(2, q2ha, q2la)
  PH2CHUNK(3, q2hb, q2lb)
  __syncthreads();   // h reads done; halfsq may overwrite hsm

  // ---- row L2 normalize ----
#pragma unroll
  for (int mt = 0; mt < 4; mt++) {
#pragma unroll
    for (int r = 0; r < 4; r++) {
      float s = 0.f;
#pragma unroll
      for (int nt = 0; nt < 4; nt++) { float v = acc2[mt][nt][r]; s += v * v; }
      s += __shfl_xor(s, 1, 64);
      s += __shfl_xor(s, 2, 64);
      s += __shfl_xor(s, 4, 64);
      s += __shfl_xor(s, 8, 64);
      if (ln == 0) halfsq[(wm * 64 + mt * 16 + quad * 4 + r) * 2 + wn] = s;
    }
  }
  __syncthreads();
#pragma unroll
  for (int mt = 0; mt < 4; mt++) {
#pragma unroll
    for (int r = 0; r < 4; r++) {
      int row = wm * 64 + mt * 16 + quad * 4 + r;
      float rinv = 1.0f / sqrtf(halfsq[row * 2] + halfsq[row * 2 + 1]);
#pragma unroll
      for (int nt = 0; nt < 4; nt++)
        Y[(m0 + row) * DD + wn * 64 + nt * 16 + ln] = acc2[mt][nt][r] * rinv;
    }
  }
}

// ---------------------------------------------------------------------------
// Symmetric KL of one D=128 row pair per 64-lane wave; inputs pre-scaled 1/T.
// sym = sum_i (pu_i - pv_i)*(au_i - av_i)  (LSE terms cancel exactly).
// No max-subtraction: args bounded (|a|<=0.25 dil, [0,1] dcl) -> exp safe.
// ---------------------------------------------------------------------------
__device__ __forceinline__ float sym_kl_row(float au0, float au1, float av0, float av1)
{
  float eu0 = __expf(au0), eu1 = __expf(au1);
  float ev0 = __expf(av0), ev1 = __expf(av1);
  float su = eu0 + eu1, sv = ev0 + ev1;
#pragma unroll
  for (int o = 32; o > 0; o >>= 1) {
    su += __shfl_xor(su, o, 64);
    sv += __shfl_xor(sv, o, 64);
  }
  float ru = 1.0f / su, rv = 1.0f / sv;
  float d0 = au0 - av0, d1 = au1 - av1;
  float part = (eu0 * ru - ev0 * rv) * d0 + (eu1 * ru - ev1 * rv) * d1;
#pragma unroll
  for (int o = 32; o > 0; o >>= 1) part += __shfl_xor(part, o, 64);
  return part;
}

// ---------------------------------------------------------------------------
// Fused loss: one wave per b. Holds p[0..11][b] in regs (float2/lane), computes
// pbar, dil, and all 12 dcl terms in ONE pass over p.
// ---------------------------------------------------------------------------
__global__ __launch_bounds__(256) void loss_kernel(
    const float* __restrict__ g, const float* __restrict__ p,
    float* __restrict__ pdil, float* __restrict__ pdcl)
{
  __shared__ float wd[4], wc[4];
  int w = threadIdx.x >> 6, lane = threadIdx.x & 63;
  int b = blockIdx.x * 4 + w;
  float2 pl[PP];
  float sx = 0.f, sy = 0.f;
#pragma unroll
  for (int l = 0; l < PP; l++) {
    pl[l] = *(const float2*)&p[((size_t)l * B_ + b) * DD + lane * 2];
    sx += pl[l].x; sy += pl[l].y;
  }
  sx *= (1.0f / PP); sy *= (1.0f / PP);
  float2 gv = *(const float2*)&g[(size_t)b * DD + lane * 2];

  float dil = sym_kl_row(gv.x * INV_T, gv.y * INV_T, sx * INV_T, sy * INV_T) * 0.125f;

  float dcl = 0.f;
#pragma unroll
  for (int l = 0; l < PP; l++) {
    float u0 = (gv.x - pl[l].x) * (gv.x - pl[l].x) * INV_T;
    float u1 = (gv.y - pl[l].y) * (gv.y - pl[l].y) * INV_T;
    float v0 = (sx - pl[l].x) * (sx - pl[l].x) * INV_T;
    float v1 = (sy - pl[l].y) * (sy - pl[l].y) * INV_T;
    dcl += sym_kl_row(u0, u1, v0, v1);
  }
  dcl *= (1.0f / 96.0f);

  if (lane == 0) { wd[w] = dil; wc[w] = dcl; }
  __syncthreads();
  if (threadIdx.x == 0) pdil[blockIdx.x] = wd[0] + wd[1] + wd[2] + wd[3];
  if (threadIdx.x == 1) pdcl[blockIdx.x] = wc[0] + wc[1] + wc[2] + wc[3];
}

__global__ __launch_bounds__(256) void final_kernel(const float* __restrict__ pdil,
                                                    const float* __restrict__ pdcl,
                                                    float* __restrict__ out)
{
  __shared__ float red[8];
  int t = threadIdx.x;
  float s0 = 0.f, s1 = 0.f;
  for (int i = t; i < 1024; i += 256) { s0 += pdil[i]; s1 += pdcl[i]; }
#pragma unroll
  for (int o = 32; o > 0; o >>= 1) {
    s0 += __shfl_xor(s0, o, 64);
    s1 += __shfl_xor(s1, o, 64);
  }
  int wid = t >> 6, lane = t & 63;
  if (lane == 0) { red[wid] = s0; red[4 + wid] = s1; }
  __syncthreads();
  if (t == 0) out[0] = red[0] + red[1] + red[2] + red[3];
  if (t == 1) out[1] = red[4] + red[5] + red[6] + red[7];
}

extern "C" void kernel_launch(void* const* d_in, const int* in_sizes, int n_in,
                              void* d_out, int out_size, void* d_ws, size_t ws_size,
                              hipStream_t stream)
{
  const float* ebg = (const float*)d_in[0];
  const float* ebp = (const float*)d_in[1];
  const float* gw1 = (const float*)d_in[3];
  const float* gb1 = (const float*)d_in[4];
  const float* gw2 = (const float*)d_in[5];
  const float* gb2 = (const float*)d_in[6];
  const float* pw1 = (const float*)d_in[7];
  const float* pb1 = (const float*)d_in[8];
  const float* pw2 = (const float*)d_in[9];
  const float* pb2 = (const float*)d_in[10];
  float* out = (float*)d_out;

  float* ws   = (float*)d_ws;
  float* g    = ws;                           // 524288 f
  float* p    = g + (size_t)B_ * DD;          // 6291456 f
  float* pdil = p + (size_t)PP * B_ * DD;     // 1024 f
  float* pdcl = pdil + 1024;                  // 1024 f
  bft* wb     = (bft*)(pdcl + 1024);
  bft* w1hg = wb;                 bft* w1lg = w1hg + 81920;
  bft* w1hp = w1lg + 81920;       bft* w1lp = w1hp + 81920;
  bft* w2hg = w1lp + 81920;       bft* w2lg = w2hg + 16384;
  bft* w2hp = w2lg + 16384;       bft* w2lp = w2hp + 16384;

  prep_kernel<<<768, 256, 0, stream>>>(gw1, pw1, gw2, pw2,
                                       w1hg, w1lg, w1hp, w1lp,
                                       w2hg, w2lg, w2hp, w2lp);
  embed_kernel<<<416, 256, 0, stream>>>(ebg, ebp,
                                        w1hg, w1lg, gb1, w2hg, w2lg, gb2,
                                        w1hp, w1lp, pb1, w2hp, w2lp, pb2,
                                        g, p);
  loss_kernel<<<B_ / 4, 256, 0, stream>>>(g, p, pdil, pdcl);
  final_kernel<<<1, 256, 0, stream>>>(pdil, pdcl, out);
}